// Round 8
// baseline (114.854 us; speedup 1.0000x reference)
//
#include <hip/hip_runtime.h>
#include <hip/hip_bf16.h>

// DenseAttentionMultiHead: out_h = Q_h @ G_bh, Q = x@W^T, G_bh = X_h^T X_h.
// B=4, S=2048, H=1024, heads=16, hd=64. 19.9 GFLOP total.
// Model H: ~70us fixed harness in-stream cost + ~45us controllable.
// R8: producers = exact R3 trio (best measured, 112.9 anchor, T_gemm=23.3
// via R5 probe). gemm_qout REWRITTEN (the one variable): it is LDS-read
// bound (64KB frag reads / 128^2-block-iter ~ 770cyc vs 320cyc MFMA; the
// __syncthreads vmcnt(0) drain idles the LDS pipe ~67% of the time).
// New structure (T3+T4 counted-vmcnt, m201-style):
//   BM=256 x BN=128, BK=64, 512 thr (8 waves 4Mx2N, 64x64/wave -- same
//   proven fragment+swizzle pattern), TRIPLE-buffered LDS 144KB (dynamic),
//   depth-2 prefetch, s_waitcnt vmcnt(12) counted (14: 6, 15: 0), raw
//   s_barrier (no drain), setprio(1) around compute. Grid (32,8)=256=1/CU,
//   XCD=bx%8 keeps A-panel sharers local. Numerics identical to R3.

typedef __bf16 bf16x8 __attribute__((ext_vector_type(8)));
typedef float f32x4 __attribute__((ext_vector_type(4)));

typedef __attribute__((address_space(3))) unsigned int lds_u32;
typedef const __attribute__((address_space(1))) unsigned int glb_u32;

__device__ __forceinline__ void gld_lds16(const void* g, void* l) {
    // async global->LDS, 16 B/lane; LDS dest = wave-uniform base + lane*16
    __builtin_amdgcn_global_load_lds((glb_u32*)g, (lds_u32*)l, 16, 0, 0);
}

__device__ __forceinline__ unsigned short f2bf(float f) {
    unsigned int u = __float_as_uint(f);
    u += 0x7FFFu + ((u >> 16) & 1u);   // RNE; inputs finite
    return (unsigned short)(u >> 16);
}

// ---------------------------------------------------------------- W + x convert + G partials
// (R3-proven, untouched.) grid (8 chunks, 64 bh) = 512 blocks.
__global__ __launch_bounds__(256) void gx_partial(
        const float* __restrict__ x, const float* __restrict__ W,
        unsigned short* __restrict__ xb, unsigned short* __restrict__ Wb,
        float* __restrict__ Gp) {
    __shared__ __align__(16) unsigned short xt[2][64 * 128];   // 32 KB dbuf
    const int tid = threadIdx.x;
    const int chunk = blockIdx.x;     // 0..7
    const int bh = blockIdx.y;        // 0..63
    const int fb = bh * 8 + chunk;    // 0..511 flat block id for W slice
    const int b = bh >> 4, h = bh & 15;
    const int wave = tid >> 6, lane = tid & 63;
    const int lm = lane & 15, quad = lane >> 4;

    {
        size_t base = (size_t)fb * 2048 + (size_t)tid * 8;
        float4 v0 = *(const float4*)&W[base];
        float4 v1 = *(const float4*)&W[base + 4];
        ushort4 o0 = {f2bf(v0.x), f2bf(v0.y), f2bf(v0.z), f2bf(v0.w)};
        ushort4 o1 = {f2bf(v1.x), f2bf(v1.y), f2bf(v1.z), f2bf(v1.w)};
        *(ushort4*)&Wb[base] = o0;
        *(ushort4*)&Wb[base + 4] = o1;
    }

    const int sc = (tid & 15) * 4;
    const int sr = tid >> 4;
    const size_t gcol = (size_t)h * 64 + sc;
    const int wsz0 = ((tid & 7) ^ 0) << 3;
    const int wsz1 = ((tid & 7) ^ 2) << 3;
    const int wsz2 = ((tid & 7) ^ 4) << 3;
    const int wsz3 = ((tid & 7) ^ 6) << 3;
    const int rA = wave * 16 + lm;
    const int swzA = ((((rA >> 2) & 7) ^ ((rA & 3) << 1)) << 3);
    int swzB[4];
    #pragma unroll
    for (int ni = 0; ni < 4; ++ni) {
        int rb = ni * 16 + lm;
        swzB[ni] = ((((rb >> 2) & 7) ^ ((rb & 3) << 1)) << 3);
    }
    const int colq = quad * 8;
    const size_t row0 = (size_t)(b * 2048 + chunk * 256);

    f32x4 acc[4] = {};
    float4 v[8];

    #pragma unroll
    for (int i = 0; i < 8; ++i)
        v[i] = *(const float4*)&x[(row0 + sr + 16 * i) * 1024 + gcol];
    #pragma unroll
    for (int i = 0; i < 8; ++i) {
        int s = sr + 16 * i;
        ushort4 o = {f2bf(v[i].x), f2bf(v[i].y), f2bf(v[i].z), f2bf(v[i].w)};
        *(ushort4*)&xb[(row0 + s) * 1024 + gcol] = o;
        xt[0][(sc + 0) * 128 + (s ^ wsz0)] = o.x;
        xt[0][(sc + 1) * 128 + (s ^ wsz1)] = o.y;
        xt[0][(sc + 2) * 128 + (s ^ wsz2)] = o.z;
        xt[0][(sc + 3) * 128 + (s ^ wsz3)] = o.w;
    }
    __syncthreads();

    #pragma unroll
    for (int i = 0; i < 8; ++i)
        v[i] = *(const float4*)&x[(row0 + 128 + sr + 16 * i) * 1024 + gcol];

    #pragma unroll
    for (int k = 0; k < 4; ++k) {
        bf16x8 af = *(const bf16x8*)&xt[0][rA * 128 + ((k * 32 + colq) ^ swzA)];
        #pragma unroll
        for (int ni = 0; ni < 4; ++ni) {
            bf16x8 bg = *(const bf16x8*)&xt[0][(ni * 16 + lm) * 128 + ((k * 32 + colq) ^ swzB[ni])];
            acc[ni] = __builtin_amdgcn_mfma_f32_16x16x32_bf16(af, bg, acc[ni], 0, 0, 0);
        }
    }

    #pragma unroll
    for (int i = 0; i < 8; ++i) {
        int s = sr + 16 * i;
        ushort4 o = {f2bf(v[i].x), f2bf(v[i].y), f2bf(v[i].z), f2bf(v[i].w)};
        *(ushort4*)&xb[(row0 + 128 + s) * 1024 + gcol] = o;
        xt[1][(sc + 0) * 128 + (s ^ wsz0)] = o.x;
        xt[1][(sc + 1) * 128 + (s ^ wsz1)] = o.y;
        xt[1][(sc + 2) * 128 + (s ^ wsz2)] = o.z;
        xt[1][(sc + 3) * 128 + (s ^ wsz3)] = o.w;
    }
    __syncthreads();

    #pragma unroll
    for (int k = 0; k < 4; ++k) {
        bf16x8 af = *(const bf16x8*)&xt[1][rA * 128 + ((k * 32 + colq) ^ swzA)];
        #pragma unroll
        for (int ni = 0; ni < 4; ++ni) {
            bf16x8 bg = *(const bf16x8*)&xt[1][(ni * 16 + lm) * 128 + ((k * 32 + colq) ^ swzB[ni])];
            acc[ni] = __builtin_amdgcn_mfma_f32_16x16x32_bf16(af, bg, acc[ni], 0, 0, 0);
        }
    }

    float* gp = Gp + ((size_t)(chunk * 64 + bh)) * 4096;
    #pragma unroll
    for (int ni = 0; ni < 4; ++ni)
        #pragma unroll
        for (int r = 0; r < 4; ++r)
            gp[(wave * 16 + quad * 4 + r) * 64 + ni * 16 + lm] = acc[ni][r];
}

// ---------------------------------------------------------------- G reduce
__global__ __launch_bounds__(256) void g_reduce(
        const float* __restrict__ Gp, unsigned short* __restrict__ Gb) {
    const int bh = blockIdx.x;
    const int e0 = blockIdx.y * 1024 + threadIdx.x * 4;
    float4 s = {0.f, 0.f, 0.f, 0.f};
    #pragma unroll
    for (int c = 0; c < 8; ++c) {
        float4 v = *(const float4*)&Gp[((size_t)(c * 64 + bh)) * 4096 + e0];
        s.x += v.x; s.y += v.y; s.z += v.z; s.w += v.w;
    }
    ushort4 o;
    o.x = f2bf(s.x); o.y = f2bf(s.y); o.z = f2bf(s.z); o.w = f2bf(s.w);
    *(ushort4*)&Gb[(size_t)bh * 4096 + e0] = o;
}

// ---------------------------------------------------------------- Q GEMM + @G epilogue
// M=8192, N=1024, K=1024. BM=256 BN=128 BK=64, 512 thr (8 waves 4Mx2N,
// 64x64/wave). Triple-buffered LDS (3 x 48KB = 144KB dynamic), depth-2
// prefetch, counted vmcnt, raw s_barrier. Same XOR swizzle + fragment
// reads as R3. Epilogue: Qt 256x136 + G2 (both heads), @G MFMA, out fp32.
__global__ __launch_bounds__(512, 1) void gemm_qout(
        const unsigned short* __restrict__ xb, const unsigned short* __restrict__ Wb,
        const unsigned short* __restrict__ Gb, float* __restrict__ out) {
    extern __shared__ __align__(16) unsigned short smem[];   // 147456 B
    const int tid = threadIdx.x;
    const int m0 = blockIdx.x * 256;      // 0..31
    const int n0 = blockIdx.y * 128;      // 0..7
    const int b  = blockIdx.x >> 3;       // 2048/256 = 8 m-blocks per batch
    const int h0 = blockIdx.y * 2;
    const int lane = tid & 63, wave = tid >> 6;
    const int wr = (wave >> 1) * 64;      // 0,64,128,192
    const int wc = (wave & 1) * 64;       // 0,64
    const int lm = lane & 15, quad = lane >> 4;
    const int srow8 = lane >> 3;          // 0..7
    const int scol = (((lane & 7) ^ (srow8 & 7))) * 8;

    const unsigned short* gaBase = &xb[(size_t)(m0 + wave * 32 + srow8) * 1024 + scol];
    const unsigned short* gbBase = &Wb[(size_t)(n0 + wave * 16 + srow8) * 1024 + scol];

    unsigned short* A0 = smem;                    // 256x64 = 16384 el
    unsigned short* B0 = smem + 16384;            // 128x64 =  8192 el
    unsigned short* A1 = smem + 24576;
    unsigned short* B1 = smem + 40960;
    unsigned short* A2 = smem + 49152;
    unsigned short* B2 = smem + 65536;

#define STAGE(pA, pB, KT)                                                     \
    {                                                                         \
        _Pragma("unroll")                                                     \
        for (int i = 0; i < 4; ++i)                                           \
            gld_lds16(gaBase + (KT) + (size_t)i * 8 * 1024,                   \
                      &(pA)[(wave * 32 + i * 8) * 64]);                       \
        _Pragma("unroll")                                                     \
        for (int i = 0; i < 2; ++i)                                           \
            gld_lds16(gbBase + (KT) + (size_t)i * 8 * 1024,                   \
                      &(pB)[(wave * 16 + i * 8) * 64]);                       \
    }

#define COMPUTE(pA, pB)                                                       \
    {                                                                         \
        _Pragma("unroll")                                                     \
        for (int kk = 0; kk < 2; ++kk) {                                      \
            bf16x8 af[4], bg[4];                                              \
            _Pragma("unroll")                                                 \
            for (int mi = 0; mi < 4; ++mi) {                                  \
                int ra = wr + mi * 16 + lm;                                   \
                int jb = (kk * 4 + quad) ^ (ra & 7);                          \
                af[mi] = *(const bf16x8*)&(pA)[ra * 64 + jb * 8];             \
            }                                                                 \
            _Pragma("unroll")                                                 \
            for (int ni = 0; ni < 4; ++ni) {                                  \
                int rb = wc + ni * 16 + lm;                                   \
                int jb = (kk * 4 + quad) ^ (rb & 7);                          \
                bg[ni] = *(const bf16x8*)&(pB)[rb * 64 + jb * 8];             \
            }                                                                 \
            _Pragma("unroll")                                                 \
            for (int mi = 0; mi < 4; ++mi)                                    \
                _Pragma("unroll")                                             \
                for (int ni = 0; ni < 4; ++ni)                                \
                    acc[mi][ni] = __builtin_amdgcn_mfma_f32_16x16x32_bf16(    \
                        af[mi], bg[ni], acc[mi][ni], 0, 0, 0);                \
        }                                                                     \
    }

    f32x4 acc[4][4] = {};
    // prologue: tiles 0,1 in flight (12 loads outstanding/wave)
    STAGE(A0, B0, 0);
    STAGE(A1, B1, 64);
    for (int t = 0; t < 16; ++t) {
        if (t < 14) {
            STAGE(A2, B2, (t + 2) * 64);
            asm volatile("s_waitcnt vmcnt(12)" ::: "memory");  // tile t landed
        } else if (t == 14) {
            asm volatile("s_waitcnt vmcnt(6)" ::: "memory");
        } else {
            asm volatile("s_waitcnt vmcnt(0)" ::: "memory");
        }
        __builtin_amdgcn_sched_barrier(0);
        asm volatile("s_barrier" ::: "memory");   // all waves' tile-t writes visible
        __builtin_amdgcn_s_setprio(1);
        COMPUTE(A0, B0);
        __builtin_amdgcn_s_setprio(0);
        asm volatile("s_barrier" ::: "memory");   // done reading before re-stage
        unsigned short* tA = A0; A0 = A1; A1 = A2; A2 = tA;
        unsigned short* tB = B0; B0 = B1; B1 = B2; B2 = tB;
    }
#undef STAGE
#undef COMPUTE

    // epilogue: Qt (256 x stride 136) wave-private quadrants; G2 both heads
    unsigned short* Qt = smem;              // 34816 el = 69632 B
    unsigned short* G2 = smem + 34816;      // 2 x 64 x 72 el = 18432 B
    #pragma unroll
    for (int mi = 0; mi < 4; ++mi)
        #pragma unroll
        for (int ni = 0; ni < 4; ++ni)
            #pragma unroll
            for (int r = 0; r < 4; ++r)
                Qt[(wr + mi * 16 + quad * 4 + r) * 136 + wc + ni * 16 + lm] =
                    f2bf(acc[mi][ni][r]);
    #pragma unroll
    for (int i = 0; i < 2; ++i) {
        int idx = tid + 512 * i;          // 2 heads x 64 rows x 8 chunks = 1024
        int hh = idx >> 9;
        int rr = (idx >> 3) & 63;
        int cc = (idx & 7) * 8;
        *(uint4*)&G2[hh * 4608 + rr * 72 + cc] =
            *(const uint4*)&Gb[((size_t)(b * 16 + h0 + hh)) * 4096 + rr * 64 + cc];
    }
    asm volatile("s_barrier" ::: "memory");   // G2 written by all, read by all
    #pragma unroll
    for (int mi = 0; mi < 4; ++mi)
        #pragma unroll
        for (int ni = 0; ni < 4; ++ni)
            acc[mi][ni] = (f32x4){0.f, 0.f, 0.f, 0.f};
    const int hh = wave & 1;              // head half of this wave's columns
    #pragma unroll
    for (int kk = 0; kk < 2; ++kk) {
        bf16x8 af[4], bg[4];
        #pragma unroll
        for (int mi = 0; mi < 4; ++mi)
            af[mi] = *(const bf16x8*)&Qt[(wr + mi * 16 + lm) * 136 + wc + kk * 32 + quad * 8];
        #pragma unroll
        for (int ni = 0; ni < 4; ++ni)   // B[k][n] = G[k][n] = G[n][k] (symmetric)
            bg[ni] = *(const bf16x8*)&G2[hh * 4608 + (ni * 16 + lm) * 72 + kk * 32 + quad * 8];
        #pragma unroll
        for (int mi = 0; mi < 4; ++mi)
            #pragma unroll
            for (int ni = 0; ni < 4; ++ni)
                acc[mi][ni] = __builtin_amdgcn_mfma_f32_16x16x32_bf16(
                    af[mi], bg[ni], acc[mi][ni], 0, 0, 0);
    }
    #pragma unroll
    for (int mi = 0; mi < 4; ++mi)
        #pragma unroll
        for (int ni = 0; ni < 4; ++ni)
            #pragma unroll
            for (int r = 0; r < 4; ++r)
                out[(size_t)(m0 + wr + mi * 16 + quad * 4 + r) * 1024
                    + n0 + wc + ni * 16 + lm] = acc[mi][ni][r];
}

// ---------------------------------------------------------------- launch
extern "C" void kernel_launch(void* const* d_in, const int* in_sizes, int n_in,
                              void* d_out, int out_size, void* d_ws, size_t ws_size,
                              hipStream_t stream) {
    const float* x = (const float*)d_in[0];   // [4,2048,1024] fp32
    const float* W = (const float*)d_in[1];   // [1024,1024] fp32
    float* out = (float*)d_out;               // [4,2048,1024] fp32
    char* ws = (char*)d_ws;
    unsigned short* xb = (unsigned short*)(ws);              // 16 MB  x bf16
    unsigned short* Wb = (unsigned short*)(ws + 16777216);   //  2 MB  W bf16
    float*          Gp = (float*)        (ws + 18874368);    //  8 MB  G partials fp32
    unsigned short* Gb = (unsigned short*)(ws + 27262976);   // 0.5 MB G bf16

    gx_partial<<<dim3(8, 64), 256, 0, stream>>>(x, W, xb, Wb, Gp);
    g_reduce<<<dim3(64, 4), 256, 0, stream>>>(Gp, Gb);
    gemm_qout<<<dim3(32, 8), 512, 147456, stream>>>(xb, Wb, Gb, out);
}